// Round 1
// 291.060 us; speedup vs baseline: 1.0777x; 1.0777x over previous
//
#include <hip/hip_runtime.h>
#include <stdint.h>

// Problem constants
#define B_     16
#define N_     512
#define R_     10
#define DE_    256
#define DR_    64
#define DOUT_  256
#define INDIM_ 3200   // (DE+DR)*R
#define BLK_   320    // DE+DR
#define RN_    5120   // R*N, K-extent of stage B
#define SPLITS_ 4     // stage B split-K factor
#define CPS_    20    // BK=64 chunks per split (80 total / 4)

typedef __bf16          v8bf  __attribute__((ext_vector_type(8)));
typedef unsigned short  v8us  __attribute__((ext_vector_type(8)));
typedef unsigned short  v4us  __attribute__((ext_vector_type(4)));
typedef float           f32x4 __attribute__((ext_vector_type(4)));

static __device__ __forceinline__ unsigned short f2b(float f) {
  union { float f; unsigned u; } c; c.f = f;
  unsigned r = c.u + 0x7FFFu + ((c.u >> 16) & 1u);   // RNE
  return (unsigned short)(r >> 16);
}

static __device__ __forceinline__ v8bf us2bf(v8us u) {
  union { v8us u; v8bf b; } c; c.u = u; return c.b;
}

// async global->LDS, 16B per lane; LDS dest = wave-uniform base + lane*16
static __device__ __forceinline__ void gl_lds16(const void* g, void* l) {
  __builtin_amdgcn_global_load_lds(
      (const __attribute__((address_space(1))) void*)g,
      (__attribute__((address_space(3))) void*)l, 16, 0, 0);
}

// ---------------- merged prep: nodeB + WnB + Uf in one launch ------------------
// blocks [0,256): node fp32->bf16 (8192 elems each)
// blocks [256,896): W node-slice -> WnB [r][o][d] bf16 (1024 elems each)
// blocks [896,1056): Uf[b][r][o] = dot(rel[b,r,:], W[o, r*320+256:+64]) (256 ea)
__global__ void prep_all(const float* __restrict__ nf, const float* __restrict__ W,
                         const float* __restrict__ rel,
                         unsigned short* __restrict__ nodeB,
                         unsigned short* __restrict__ WnB,
                         float* __restrict__ Uf) {
  const int bb = blockIdx.x;
  const int tid = threadIdx.x;
  if (bb < 256) {
    const size_t base = (size_t)bb * 8192;
#pragma unroll
    for (int p = 0; p < 4; ++p) {
      size_t off = base + (size_t)p * 2048 + (size_t)tid * 8;
      float4 x = *(const float4*)(nf + off);
      float4 y = *(const float4*)(nf + off + 4);
      v8us u;
      u[0] = f2b(x.x); u[1] = f2b(x.y); u[2] = f2b(x.z); u[3] = f2b(x.w);
      u[4] = f2b(y.x); u[5] = f2b(y.y); u[6] = f2b(y.z); u[7] = f2b(y.w);
      *(v8us*)(nodeB + off) = u;
    }
  } else if (bb < 896) {
    int idx = (bb - 256) * 1024 + tid * 4;          // < 655360, 4-aligned
    int r = idx >> 16;
    int o = (idx >> 8) & 255;
    int d = idx & 255;                               // 4-aligned, stays in row
    float4 x = *(const float4*)(W + (size_t)o * INDIM_ + r * BLK_ + d);
    v4us u;
    u[0] = f2b(x.x); u[1] = f2b(x.y); u[2] = f2b(x.z); u[3] = f2b(x.w);
    *(v4us*)(WnB + idx) = u;
  } else {
    int idx = (bb - 896) * 256 + tid;                // < B*R*DOUT = 40960
    int o  = idx & 255;
    int br = idx >> 8;                                // b*R + r
    int r  = br % R_;
    const float* rp = rel + (size_t)br * DR_;
    const float* wp = W + (size_t)o * INDIM_ + r * BLK_ + DE_;
    float v = 0.f;
#pragma unroll 8
    for (int d = 0; d < DR_; ++d) v += rp[d] * wp[d];
    Uf[idx] = v;
  }
}

// ---------------- stage A: G'[b][o][(r,m)] = Wn[r] @ nodeB[b]^T + U ------------
// Per (b,r): M=256 (o), N=512 (m), K=256 (d). 128x128 tile, BK=64, 4 waves 2x2.
// Both operands bf16 via global_load_lds. Epilogue: LDS transpose (aliasing the
// 32 KB staging buffers) -> coalesced dwordx4 stores of bf16 G'.
__global__ void stageA_gemm(const unsigned short* __restrict__ nodeB,
                            const unsigned short* __restrict__ WnB,
                            const float* __restrict__ Uf,
                            unsigned short* __restrict__ Gp) {
  __shared__ unsigned short S[128 * 128];   // 32 KB: staging (Al|Bl) then C-tile
  unsigned short* Al = S;                   // 128x64 Wn rows (o)
  unsigned short* Bl = S + 128 * 64;        // 128x64 node rows (m)
  const int br = blockIdx.x;                // b*R + r
  const int b  = br / R_, r = br % R_;
  const int o0 = blockIdx.y * 128;
  const int m0 = blockIdx.z * 128;
  const int tid  = threadIdx.x;
  const int lane = tid & 63;
  const int wave = tid >> 6;
  const int wm = wave >> 1, wn = wave & 1;
  const int quad = lane >> 4, l16 = lane & 15;

  const unsigned short* Wb = WnB + (size_t)r * (DOUT_ * DE_);
  const unsigned short* Nb = nodeB + (size_t)b * (N_ * DE_);

  f32x4 acc[4][4];
#pragma unroll
  for (int i = 0; i < 4; ++i)
#pragma unroll
    for (int j = 0; j < 4; ++j) acc[i][j] = f32x4{0.f, 0.f, 0.f, 0.f};

  for (int dk = 0; dk < DE_; dk += 64) {
#pragma unroll
    for (int it = 0; it < 4; ++it) {
      int rowblk = it * 32 + wave * 8;
      int rl = rowblk + (lane >> 3);
      int kc = (lane & 7) ^ (rl & 7);
      gl_lds16(Wb + (size_t)(o0 + rl) * DE_ + dk + kc * 8, Al + rowblk * 64);
      gl_lds16(Nb + (size_t)(m0 + rl) * DE_ + dk + kc * 8, Bl + rowblk * 64);
    }
    __syncthreads();
#pragma unroll
    for (int ks = 0; ks < 2; ++ks) {
      const int kb = ks * 4;
      v8bf av[4], bv[4];
#pragma unroll
      for (int mi = 0; mi < 4; ++mi) {
        int m = wm * 64 + mi * 16 + l16;
        av[mi] = us2bf(*(const v8us*)(Al + m * 64 + (((kb + quad) ^ (m & 7)) * 8)));
      }
#pragma unroll
      for (int ni = 0; ni < 4; ++ni) {
        int c = wn * 64 + ni * 16 + l16;
        bv[ni] = us2bf(*(const v8us*)(Bl + c * 64 + (((kb + quad) ^ (c & 7)) * 8)));
      }
#pragma unroll
      for (int mi = 0; mi < 4; ++mi)
#pragma unroll
        for (int ni = 0; ni < 4; ++ni)
          acc[mi][ni] = __builtin_amdgcn_mfma_f32_16x16x32_bf16(av[mi], bv[ni], acc[mi][ni], 0, 0, 0);
    }
    __syncthreads();
  }

  // epilogue: C tile -> LDS (bf16, +U), then coalesced 16B stores to G'
#pragma unroll
  for (int mi = 0; mi < 4; ++mi)
#pragma unroll
    for (int t = 0; t < 4; ++t) {
      int o_loc = wm * 64 + mi * 16 + quad * 4 + t;
      float u = Uf[(size_t)br * DOUT_ + o0 + o_loc];
#pragma unroll
      for (int ni = 0; ni < 4; ++ni) {
        int m_loc = wn * 64 + ni * 16 + l16;
        S[o_loc * 128 + m_loc] = f2b(acc[mi][ni][t] + u);
      }
    }
  __syncthreads();
#pragma unroll
  for (int p = 0; p < 8; ++p) {
    int idx16 = p * 2048 + tid * 8;         // u16 index into S
    int orow = idx16 >> 7;                  // 0..127
    int moff = idx16 & 127;
    unsigned short* dst = Gp + ((size_t)(b * DOUT_ + o0 + orow)) * RN_ + r * N_ + m0 + moff;
    *(v8us*)dst = *(const v8us*)(S + idx16);
  }
}

// ---------------- stage B v2: part[sp][b] = adj(fp32) @ G' slice ---------------
// Tile 128(n) x 256(o full DOUT), BK=64, split-K=4 (20 chunks/block).
// Grid 16x4x4 = 256 blocks (1/CU), 512 thr (8 waves 2x4, each 64n x 64o).
// Double-buffered LDS (96 KB): single barrier per K-step; next tile's
// global_load_lds (B) + adj register loads (A) are issued BEFORE the MFMA
// phase, A convert/ds_write lands AFTER it -> load latency hides under compute.
__global__ __launch_bounds__(512, 2)
void stageB_gemm(const float* __restrict__ adj,
                 const unsigned short* __restrict__ Gp,
                 float* __restrict__ part) {
  // per buffer: A 128x64 (8192 u16) + B 256x64 (16384 u16) = 24576 u16 (48 KB)
  __shared__ unsigned short SB[2 * 24576];  // 96 KB -> 1 block/CU, 8 waves
  const int b  = blockIdx.x;
  const int n0 = blockIdx.y * 128;
  const int sp = blockIdx.z;                // chunks [sp*20, sp*20+20)
  const int tid  = threadIdx.x;
  const int lane = tid & 63;
  const int wave = tid >> 6;
  const int wm = wave >> 2;                 // 0..1 : n 64-row half
  const int wn = wave & 3;                  // 0..3 : o 64-col quarter
  const int quad = lane >> 4, l16 = lane & 15;

  const float* Ab = adj + (size_t)b * (R_ * N_ * N_);
  const unsigned short* Gb = Gp + (size_t)b * (DOUT_ * RN_);

  f32x4 acc[4][4];
#pragma unroll
  for (int i = 0; i < 4; ++i)
#pragma unroll
    for (int j = 0; j < 4; ++j) acc[i][j] = f32x4{0.f, 0.f, 0.f, 0.f};

  // A staging: thread covers rows {ar0, ar0+64}, 8 floats each at col ac8*8
  const int ar0 = tid >> 3;                 // 0..63
  const int ac8 = tid & 7;
  const int acs = ac8 ^ (ar0 & 7);          // XOR slot ((ar0+64)&7 == ar0&7)
  // B staging: per issue-round s, wave covers rows [s*64+wave*8, +8)
  const int brl = wave * 8 + (lane >> 3);
  const int bkc = lane & 7;

  int c = sp * CPS_;                        // current BK=64 chunk id (k = c*64)

  // ---- prologue: stage chunk c into buf0
  {
    const int r = c >> 3, m0 = (c & 7) << 6, k0 = c << 6;
    unsigned short* Aln = SB;
    unsigned short* Bln = SB + 128 * 64;
#pragma unroll
    for (int s = 0; s < 4; ++s) {
      int rl = s * 64 + brl;
      int kc = bkc ^ (rl & 7);
      gl_lds16(Gb + (size_t)rl * RN_ + k0 + kc * 8, Bln + (s * 64 + wave * 8) * 64);
    }
    const float* Ap = Ab + ((size_t)r * N_ + n0) * N_ + m0;
    float4 a0 = *(const float4*)(Ap + (size_t)ar0 * N_ + ac8 * 8);
    float4 a1 = *(const float4*)(Ap + (size_t)ar0 * N_ + ac8 * 8 + 4);
    float4 a2 = *(const float4*)(Ap + (size_t)(ar0 + 64) * N_ + ac8 * 8);
    float4 a3 = *(const float4*)(Ap + (size_t)(ar0 + 64) * N_ + ac8 * 8 + 4);
    v8us u0, u1;
    u0[0] = f2b(a0.x); u0[1] = f2b(a0.y); u0[2] = f2b(a0.z); u0[3] = f2b(a0.w);
    u0[4] = f2b(a1.x); u0[5] = f2b(a1.y); u0[6] = f2b(a1.z); u0[7] = f2b(a1.w);
    u1[0] = f2b(a2.x); u1[1] = f2b(a2.y); u1[2] = f2b(a2.z); u1[3] = f2b(a2.w);
    u1[4] = f2b(a3.x); u1[5] = f2b(a3.y); u1[6] = f2b(a3.z); u1[7] = f2b(a3.w);
    *(v8us*)(Aln + ar0 * 64 + acs * 8) = u0;
    *(v8us*)(Aln + (ar0 + 64) * 64 + acs * 8) = u1;
  }
  __syncthreads();

  for (int t = 0; t < CPS_; ++t) {
    unsigned short* Sc = SB + (t & 1) * 24576;        // compute buffer
    unsigned short* Sn = SB + ((t & 1) ^ 1) * 24576;  // prefetch buffer
    float4 a0, a1, a2, a3;
    const bool pf = (t + 1 < CPS_);
    if (pf) {
      const int c1 = c + 1;
      const int r = c1 >> 3, m0 = (c1 & 7) << 6, k0 = c1 << 6;
      unsigned short* Bln = Sn + 128 * 64;
#pragma unroll
      for (int s = 0; s < 4; ++s) {
        int rl = s * 64 + brl;
        int kc = bkc ^ (rl & 7);
        gl_lds16(Gb + (size_t)rl * RN_ + k0 + kc * 8, Bln + (s * 64 + wave * 8) * 64);
      }
      const float* Ap = Ab + ((size_t)r * N_ + n0) * N_ + m0;
      a0 = *(const float4*)(Ap + (size_t)ar0 * N_ + ac8 * 8);
      a1 = *(const float4*)(Ap + (size_t)ar0 * N_ + ac8 * 8 + 4);
      a2 = *(const float4*)(Ap + (size_t)(ar0 + 64) * N_ + ac8 * 8);
      a3 = *(const float4*)(Ap + (size_t)(ar0 + 64) * N_ + ac8 * 8 + 4);
    }
    // compute current buffer
    const unsigned short* Alc = Sc;
    const unsigned short* Blc = Sc + 128 * 64;
#pragma unroll
    for (int ks = 0; ks < 2; ++ks) {
      const int kb = ks * 4;
      v8bf av[4], bv[4];
#pragma unroll
      for (int mi = 0; mi < 4; ++mi) {
        int m = wm * 64 + mi * 16 + l16;
        av[mi] = us2bf(*(const v8us*)(Alc + m * 64 + (((kb + quad) ^ (m & 7)) * 8)));
      }
#pragma unroll
      for (int ni = 0; ni < 4; ++ni) {
        int o = wn * 64 + ni * 16 + l16;
        bv[ni] = us2bf(*(const v8us*)(Blc + o * 64 + (((kb + quad) ^ (o & 7)) * 8)));
      }
#pragma unroll
      for (int mi = 0; mi < 4; ++mi)
#pragma unroll
        for (int ni = 0; ni < 4; ++ni)
          acc[mi][ni] = __builtin_amdgcn_mfma_f32_16x16x32_bf16(av[mi], bv[ni], acc[mi][ni], 0, 0, 0);
    }
    // A regs arrived during compute: convert -> next buffer
    if (pf) {
      v8us u0, u1;
      u0[0] = f2b(a0.x); u0[1] = f2b(a0.y); u0[2] = f2b(a0.z); u0[3] = f2b(a0.w);
      u0[4] = f2b(a1.x); u0[5] = f2b(a1.y); u0[6] = f2b(a1.z); u0[7] = f2b(a1.w);
      u1[0] = f2b(a2.x); u1[1] = f2b(a2.y); u1[2] = f2b(a2.z); u1[3] = f2b(a2.w);
      u1[4] = f2b(a3.x); u1[5] = f2b(a3.y); u1[6] = f2b(a3.z); u1[7] = f2b(a3.w);
      *(v8us*)(Sn + ar0 * 64 + acs * 8) = u0;
      *(v8us*)(Sn + (ar0 + 64) * 64 + acs * 8) = u1;
    }
    __syncthreads();   // drains vmcnt (B gl_lds) + lgkm (A ds_write)
    ++c;
  }

  // epilogue: plain coalesced stores to this split's private partial buffer
  float* pb = part + (((size_t)sp * B_ + b) * N_) * DOUT_;
#pragma unroll
  for (int mi = 0; mi < 4; ++mi)
#pragma unroll
    for (int t4 = 0; t4 < 4; ++t4) {
      int row = n0 + wm * 64 + mi * 16 + quad * 4 + t4;
#pragma unroll
      for (int ni = 0; ni < 4; ++ni) {
        int col = wn * 64 + ni * 16 + l16;
        pb[(size_t)row * DOUT_ + col] = acc[mi][ni][t4];
      }
    }
}

// ---------------- reduce: out = bias + sum_sp part[sp] -------------------------
__global__ void reduce_out(const float* __restrict__ part, const float* __restrict__ bias,
                           float* __restrict__ out) {
  const size_t idx = (size_t)blockIdx.x * 256 + threadIdx.x;  // float4 index
  const size_t stride = (size_t)B_ * N_ * DOUT_ / 4;          // 524288
  f32x4 a = *(const f32x4*)(bias + (idx & 63) * 4);
#pragma unroll
  for (int s = 0; s < SPLITS_; ++s) {
    f32x4 p = *(const f32x4*)((const float*)part + (stride * s + idx) * 4);
    a += p;
  }
  *(f32x4*)(out + idx * 4) = a;
}

// ---------------- launch -------------------------------------------------------
extern "C" void kernel_launch(void* const* d_in, const int* in_sizes, int n_in,
                              void* d_out, int out_size, void* d_ws, size_t ws_size,
                              hipStream_t stream) {
  const float* node = (const float*)d_in[0];
  const float* rel  = (const float*)d_in[1];
  const float* adj  = (const float*)d_in[2];
  const float* W    = (const float*)d_in[3];
  const float* bias = (const float*)d_in[4];
  float* out = (float*)d_out;

  char* ws = (char*)d_ws;
  // layout (~80 MB total):
  unsigned short* nodeB = (unsigned short*)(ws);                      // 4 MB
  unsigned short* WnB   = (unsigned short*)(ws + ((size_t)5 << 20));  // 1.25 MB
  float*          Uf    = (float*)         (ws + ((size_t)7 << 20));  // 160 KB
  unsigned short* Gp    = (unsigned short*)(ws + ((size_t)8 << 20));  // 40 MB
  float*          part  = (float*)         (ws + ((size_t)48 << 20)); // 32 MB (4 x 8MB)

  prep_all<<<dim3(1056), 256, 0, stream>>>(node, W, rel, nodeB, WnB, Uf);
  stageA_gemm<<<dim3(B_ * R_, DOUT_ / 128, N_ / 128), 256, 0, stream>>>(nodeB, WnB, Uf, Gp);
  stageB_gemm<<<dim3(B_, N_ / 128, SPLITS_), 512, 0, stream>>>(adj, Gp, part);
  reduce_out<<<dim3((B_ * N_ * DOUT_ / 4) / 256), 256, 0, stream>>>(part, bias, out);
}